// Round 10
// baseline (71.944 us; speedup 1.0000x reference)
//
#include <hip/hip_runtime.h>
#include <stdint.h>

// ContrastiveLoss: B=8192, D=1024, n=2048, T=0.5
// K1: row-normalize f32 -> fp8 e4m3, stored in MFMA-native 2KB "units":
//     unit u = (row16, kt) covers rows [row16*16,+16) x k-bytes [kt*128,+128);
//     within unit: gemm-lane gl's 32B split as lo16 at gl*16, hi16 at 1024+gl*16,
//     where gl = (kg*16 + r), r=row&15, kg=(k>>5)&3.
// K2: NO-LDS, NO-BARRIER 128x128 MX-fp8 GEMM: operands loaded straight from
//     L2 via two dense global_load_dwordx4 per fragment; 16 loads + 16 MFMA
//     per wave per K-tile; XCD-chunked mapping; epilogue: exp-row-sum + triu.
// K3: scalar finalize

#define BDIM 1024
#define BROWS 8192
#define NROWS 2048

#define BM 128
#define BN 128
#define NKT 8              // K-tiles of 128 fp8 elems

typedef __attribute__((ext_vector_type(4))) int i32x4;
typedef __attribute__((ext_vector_type(8))) int i32x8;
typedef __attribute__((ext_vector_type(4))) float f32x4;

// float -> OCP e4m3fn, RNE, handles subnormals (|x| <= 1 for our data)
static __device__ __forceinline__ unsigned char f2e4m3(float x) {
  uint32_t u = __float_as_uint(x);
  uint32_t s = (u >> 24) & 0x80u;
  uint32_t a = u & 0x7fffffffu;
  if (a == 0) return (unsigned char)s;
  int e = (int)(a >> 23) - 127;
  uint32_t m = a & 0x7fffffu;
  if (e >= -6) {
    uint32_t keep = m >> 20;
    uint32_t rest = m & 0xfffffu;
    keep += (rest > 0x80000u) || (rest == 0x80000u && (keep & 1u));
    uint32_t v = ((uint32_t)(e + 7) << 3) + keep;
    return (unsigned char)(s | v);
  }
  if (e < -10) return (unsigned char)s;
  uint32_t full = 0x800000u | m;
  int sh = 14 - e;
  uint32_t keep = full >> sh;
  uint32_t rest = full & ((1u << sh) - 1u);
  uint32_t half = 1u << (sh - 1);
  keep += (rest > half) || (rest == half && (keep & 1u));
  return (unsigned char)(s | keep);
}

static __device__ __forceinline__ uint32_t pk4(float4 v, float inv) {
  return (uint32_t)f2e4m3(v.x * inv) | ((uint32_t)f2e4m3(v.y * inv) << 8) |
         ((uint32_t)f2e4m3(v.z * inv) << 16) | ((uint32_t)f2e4m3(v.w * inv) << 24);
}

__global__ __launch_bounds__(256) void normalize_kernel(const float* __restrict__ emb,
                                                        unsigned char* __restrict__ zb,
                                                        float* __restrict__ denom,
                                                        float* __restrict__ sumsim) {
  const int w = threadIdx.x >> 6;
  const int lane = threadIdx.x & 63;
  const int row = blockIdx.x * 4 + w;
  const float4* src = reinterpret_cast<const float4*>(emb + (size_t)row * BDIM);
  // lane owns elems [lane*16, +16) = one 16B fp8 granule
  float4 v[4];
  float ss = 0.f;
#pragma unroll
  for (int i = 0; i < 4; i++) {
    v[i] = src[lane * 4 + i];
    ss += v[i].x * v[i].x + v[i].y * v[i].y + v[i].z * v[i].z + v[i].w * v[i].w;
  }
#pragma unroll
  for (int m = 1; m < 64; m <<= 1) ss += __shfl_xor(ss, m);
  const float inv = rsqrtf(ss);
  uint4 o;
  o.x = pk4(v[0], inv);
  o.y = pk4(v[1], inv);
  o.z = pk4(v[2], inv);
  o.w = pk4(v[3], inv);
  // unit layout: unit = (row>>4)*8 + (lane>>3); within unit:
  //   h = lane&1, gl = ((lane>>1)&3)*16 + (row&15); off = h*1024 + gl*16
  const size_t unit = (size_t)(row >> 4) * 8 + (lane >> 3);
  const int off = (lane & 1) * 1024 + ((((lane >> 1) & 3) * 16 + (row & 15)) * 16);
  *reinterpret_cast<uint4*>(zb + unit * 2048 + off) = o;
  if (blockIdx.x < NROWS / 4 && lane == 0) denom[row] = 0.f;
  if (blockIdx.x == 0 && threadIdx.x == 0) sumsim[0] = 0.f;
}

// ---------------- GEMM: no LDS, no barriers ----------------
// gemm lane l reads fragment for (r=l&15, kg=l>>4) of unit (row16, kt):
//   lo = unit_base + l*16, hi = unit_base + 1024 + l*16  (both dense/coalesced)

__global__ __launch_bounds__(256) void gemm_fused(const unsigned char* __restrict__ zb,
                                                  float* __restrict__ denom,
                                                  float* __restrict__ sumsim) {
  // XCD-chunked: xcd owns 8 j-blocks x all 16 i-blocks
  const int bx = blockIdx.x;            // 0..1023
  const int xcd = bx & 7;
  const int idx = bx >> 3;              // 0..127
  const int jb = xcd * 8 + (idx & 7);   // 0..63
  const int ib = idx >> 3;              // 0..15
  const int i0 = ib * BM;               // [0,2048)
  const int j0 = jb * BN;               // [0,8192)

  const int t = threadIdx.x;
  const int lane = t & 63;
  const int w = t >> 6;                 // 0..3
  const int WR = w >> 1;                // 0..1
  const int WC = w & 1;                 // 0..1

  const int ai16 = (i0 >> 4) + WR * 4;  // A unit row16 base (4 units: mm 0..3)
  const int bj16 = (j0 >> 4) + WC * 4;  // B unit row16 base (4 units: nn 0..3)

  const unsigned char* ap = zb + (size_t)ai16 * 8 * 2048 + lane * 16;
  const unsigned char* bp = zb + (size_t)bj16 * 8 * 2048 + lane * 16;

  f32x4 acc[4][4] = {};

#define RD32(dst, p)                                             \
  {                                                              \
    const i32x4 lo_ = *reinterpret_cast<const i32x4*>(p);        \
    const i32x4 hi_ = *reinterpret_cast<const i32x4*>((p) + 1024); \
    dst[0] = lo_[0]; dst[1] = lo_[1]; dst[2] = lo_[2]; dst[3] = lo_[3]; \
    dst[4] = hi_[0]; dst[5] = hi_[1]; dst[6] = hi_[2]; dst[7] = hi_[3]; \
  }

#pragma unroll 1
  for (int kt = 0; kt < NKT; ++kt) {
    const size_t ko = (size_t)kt * 2048;
    i32x8 bb[4];
#pragma unroll
    for (int nn = 0; nn < 4; nn++) {
      RD32(bb[nn], bp + (size_t)nn * 8 * 2048 + ko);
    }
#pragma unroll
    for (int mm = 0; mm < 4; mm++) {
      i32x8 aa;
      RD32(aa, ap + (size_t)mm * 8 * 2048 + ko);
#pragma unroll
      for (int nn = 0; nn < 4; nn++) {
        acc[mm][nn] = __builtin_amdgcn_mfma_scale_f32_16x16x128_f8f6f4(
            aa, bb[nn], acc[mm][nn], 0, 0, 0, 0x7f7f7f7f, 0, 0x7f7f7f7f);
      }
    }
  }

  // ---- epilogue: C/D layout col=lane&15, row=(lane>>4)*4+reg ----
  const int hi4 = lane >> 4;
  const int col_l = lane & 15;
  float ssim = 0.f;
#pragma unroll
  for (int m = 0; m < 4; m++) {
    const int gibase = i0 + WR * 64 + m * 16 + hi4 * 4;
#pragma unroll
    for (int r = 0; r < 4; r++) {
      const int gi = gibase + r;
      float dsum = 0.f;
#pragma unroll
      for (int n = 0; n < 4; n++) {
        const int gj = j0 + WC * 64 + n * 16 + col_l;
        const float s = acc[m][n][r] * 2.0f;
        const float e = __expf(s);
        if (gj != gi) dsum += e;               // denom excludes diagonal
        if (gj < NROWS && gi < gj) ssim += s;  // triu(rows[:, :n], k=1)
      }
      dsum += __shfl_xor(dsum, 1);
      dsum += __shfl_xor(dsum, 2);
      dsum += __shfl_xor(dsum, 4);
      dsum += __shfl_xor(dsum, 8);
      if (col_l == 0) atomicAdd(&denom[gi], dsum);
    }
  }
#pragma unroll
  for (int msk = 1; msk < 64; msk <<= 1) ssim += __shfl_xor(ssim, msk);
  if (lane == 0 && j0 < NROWS) atomicAdd(sumsim, ssim);
}

__global__ __launch_bounds__(1024) void finalize(const float* __restrict__ denom,
                                                 const float* __restrict__ sumsim,
                                                 float* __restrict__ out) {
  const int t = threadIdx.x;
  double s = 0.0;
#pragma unroll
  for (int i = t; i < NROWS; i += 1024) {
    s += (double)(NROWS - 1 - i) * log((double)denom[i]);
  }
#pragma unroll
  for (int m = 1; m < 64; m <<= 1) s += __shfl_xor(s, m);
  __shared__ double ws_[16];
  if ((t & 63) == 0) ws_[t >> 6] = s;
  __syncthreads();
  if (t == 0) {
    double tot = 0.0;
#pragma unroll
    for (int i = 0; i < 16; i++) tot += ws_[i];
    const double loss = tot - (double)sumsim[0];
    out[0] = (float)(-2.0 / (double)NROWS * (double)(NROWS - 1) * loss);
  }
}

extern "C" void kernel_launch(void* const* d_in, const int* in_sizes, int n_in,
                              void* d_out, int out_size, void* d_ws, size_t ws_size,
                              hipStream_t stream) {
  const float* emb = (const float*)d_in[0];
  unsigned char* zb = (unsigned char*)d_ws;
  float* denom = (float*)((char*)d_ws + (size_t)BROWS * BDIM);  // 8 MB fp8
  float* sumsim = denom + NROWS;
  float* out = (float*)d_out;

  normalize_kernel<<<BROWS / 4, 256, 0, stream>>>(emb, zb, denom, sumsim);
  gemm_fused<<<(NROWS / BM) * (BROWS / BN), 256, 0, stream>>>(zb, denom, sumsim);
  finalize<<<1, 1024, 0, stream>>>(denom, sumsim, out);
}

// Round 11
// 64.437 us; speedup vs baseline: 1.1165x; 1.1165x over previous
//
#include <hip/hip_runtime.h>
#include <stdint.h>

// ContrastiveLoss: B=8192, D=1024, n=2048, T=0.5
// K1: row-normalize f32 -> fp8 e4m3, stored in MFMA-native 2KB "units":
//     unit u = (row16, kt) covers rows [row16*16,+16) x k-bytes [kt*128,+128);
//     within unit: gemm-lane gl's 32B split as lo16 at gl*16, hi16 at 1024+gl*16.
// K2: NO-LDS, NO-BARRIER 128x128 MX-fp8 GEMM, __launch_bounds__(256,4) so
//     bb[4] B-fragments stay register-resident (R10 at VGPR=80 re-materialized
//     them -> 4x L2 traffic -> L2-BW-bound). 16 loads + 16 MFMA per wave/K-tile.
// K3: scalar finalize

#define BDIM 1024
#define BROWS 8192
#define NROWS 2048

#define BM 128
#define BN 128
#define NKT 8              // K-tiles of 128 fp8 elems

typedef __attribute__((ext_vector_type(4))) int i32x4;
typedef __attribute__((ext_vector_type(8))) int i32x8;
typedef __attribute__((ext_vector_type(4))) float f32x4;

// float -> OCP e4m3fn, RNE, handles subnormals (|x| <= 1 for our data)
static __device__ __forceinline__ unsigned char f2e4m3(float x) {
  uint32_t u = __float_as_uint(x);
  uint32_t s = (u >> 24) & 0x80u;
  uint32_t a = u & 0x7fffffffu;
  if (a == 0) return (unsigned char)s;
  int e = (int)(a >> 23) - 127;
  uint32_t m = a & 0x7fffffu;
  if (e >= -6) {
    uint32_t keep = m >> 20;
    uint32_t rest = m & 0xfffffu;
    keep += (rest > 0x80000u) || (rest == 0x80000u && (keep & 1u));
    uint32_t v = ((uint32_t)(e + 7) << 3) + keep;
    return (unsigned char)(s | v);
  }
  if (e < -10) return (unsigned char)s;
  uint32_t full = 0x800000u | m;
  int sh = 14 - e;
  uint32_t keep = full >> sh;
  uint32_t rest = full & ((1u << sh) - 1u);
  uint32_t half = 1u << (sh - 1);
  keep += (rest > half) || (rest == half && (keep & 1u));
  return (unsigned char)(s | keep);
}

static __device__ __forceinline__ uint32_t pk4(float4 v, float inv) {
  return (uint32_t)f2e4m3(v.x * inv) | ((uint32_t)f2e4m3(v.y * inv) << 8) |
         ((uint32_t)f2e4m3(v.z * inv) << 16) | ((uint32_t)f2e4m3(v.w * inv) << 24);
}

__global__ __launch_bounds__(256) void normalize_kernel(const float* __restrict__ emb,
                                                        unsigned char* __restrict__ zb,
                                                        float* __restrict__ denom,
                                                        float* __restrict__ sumsim) {
  const int w = threadIdx.x >> 6;
  const int lane = threadIdx.x & 63;
  const int row = blockIdx.x * 4 + w;
  const float4* src = reinterpret_cast<const float4*>(emb + (size_t)row * BDIM);
  float4 v[4];
  float ss = 0.f;
#pragma unroll
  for (int i = 0; i < 4; i++) {
    v[i] = src[lane * 4 + i];
    ss += v[i].x * v[i].x + v[i].y * v[i].y + v[i].z * v[i].z + v[i].w * v[i].w;
  }
#pragma unroll
  for (int m = 1; m < 64; m <<= 1) ss += __shfl_xor(ss, m);
  const float inv = rsqrtf(ss);
  uint4 o;
  o.x = pk4(v[0], inv);
  o.y = pk4(v[1], inv);
  o.z = pk4(v[2], inv);
  o.w = pk4(v[3], inv);
  // unit layout: unit = (row>>4)*8 + (lane>>3); within unit:
  //   h = lane&1, gl = ((lane>>1)&3)*16 + (row&15); off = h*1024 + gl*16
  const size_t unit = (size_t)(row >> 4) * 8 + (lane >> 3);
  const int off = (lane & 1) * 1024 + ((((lane >> 1) & 3) * 16 + (row & 15)) * 16);
  *reinterpret_cast<uint4*>(zb + unit * 2048 + off) = o;
  if (blockIdx.x < NROWS / 4 && lane == 0) denom[row] = 0.f;
  if (blockIdx.x == 0 && threadIdx.x == 0) sumsim[0] = 0.f;
}

// ---------------- GEMM: no LDS, no barriers ----------------
// gemm lane l reads fragment for (r=l&15, kg=l>>4) of unit (row16, kt):
//   lo = unit_base + l*16, hi = unit_base + 1024 + l*16  (both dense/coalesced)

__global__ __launch_bounds__(256, 4) void gemm_fused(const unsigned char* __restrict__ zb,
                                                     float* __restrict__ denom,
                                                     float* __restrict__ sumsim) {
  // XCD-chunked: xcd owns 8 j-blocks x all 16 i-blocks (~3MB working set / L2)
  const int bx = blockIdx.x;            // 0..1023
  const int xcd = bx & 7;
  const int idx = bx >> 3;              // 0..127
  const int jb = xcd * 8 + (idx & 7);   // 0..63
  const int ib = idx >> 3;              // 0..15
  const int i0 = ib * BM;               // [0,2048)
  const int j0 = jb * BN;               // [0,8192)

  const int t = threadIdx.x;
  const int lane = t & 63;
  const int w = t >> 6;                 // 0..3
  const int WR = w >> 1;                // 0..1
  const int WC = w & 1;                 // 0..1

  const int ai16 = (i0 >> 4) + WR * 4;  // A unit row16 base (4 units: mm 0..3)
  const int bj16 = (j0 >> 4) + WC * 4;  // B unit row16 base (4 units: nn 0..3)

  const unsigned char* __restrict__ ap = zb + (size_t)ai16 * 8 * 2048 + lane * 16;
  const unsigned char* __restrict__ bp = zb + (size_t)bj16 * 8 * 2048 + lane * 16;

  f32x4 acc[4][4] = {};

#define RD32(dst, p)                                                    \
  {                                                                     \
    const i32x4 lo_ = *reinterpret_cast<const i32x4*>(p);               \
    const i32x4 hi_ = *reinterpret_cast<const i32x4*>((p) + 1024);      \
    dst[0] = lo_[0]; dst[1] = lo_[1]; dst[2] = lo_[2]; dst[3] = lo_[3]; \
    dst[4] = hi_[0]; dst[5] = hi_[1]; dst[6] = hi_[2]; dst[7] = hi_[3]; \
  }

#pragma unroll 1
  for (int kt = 0; kt < NKT; ++kt) {
    const size_t ko = (size_t)kt * 2048;
    i32x8 bb[4];
#pragma unroll
    for (int nn = 0; nn < 4; nn++) {
      RD32(bb[nn], bp + (size_t)nn * 8 * 2048 + ko);
    }
#pragma unroll
    for (int mm = 0; mm < 4; mm++) {
      i32x8 aa;
      RD32(aa, ap + (size_t)mm * 8 * 2048 + ko);
#pragma unroll
      for (int nn = 0; nn < 4; nn++) {
        acc[mm][nn] = __builtin_amdgcn_mfma_scale_f32_16x16x128_f8f6f4(
            aa, bb[nn], acc[mm][nn], 0, 0, 0, 0x7f7f7f7f, 0, 0x7f7f7f7f);
      }
    }
  }

  // ---- epilogue: C/D layout col=lane&15, row=(lane>>4)*4+reg ----
  const int hi4 = lane >> 4;
  const int col_l = lane & 15;
  float ssim = 0.f;
#pragma unroll
  for (int m = 0; m < 4; m++) {
    const int gibase = i0 + WR * 64 + m * 16 + hi4 * 4;
#pragma unroll
    for (int r = 0; r < 4; r++) {
      const int gi = gibase + r;
      float dsum = 0.f;
#pragma unroll
      for (int n = 0; n < 4; n++) {
        const int gj = j0 + WC * 64 + n * 16 + col_l;
        const float s = acc[m][n][r] * 2.0f;
        const float e = __expf(s);
        if (gj != gi) dsum += e;               // denom excludes diagonal
        if (gj < NROWS && gi < gj) ssim += s;  // triu(rows[:, :n], k=1)
      }
      dsum += __shfl_xor(dsum, 1);
      dsum += __shfl_xor(dsum, 2);
      dsum += __shfl_xor(dsum, 4);
      dsum += __shfl_xor(dsum, 8);
      if (col_l == 0) atomicAdd(&denom[gi], dsum);
    }
  }
#pragma unroll
  for (int msk = 1; msk < 64; msk <<= 1) ssim += __shfl_xor(ssim, msk);
  if (lane == 0 && j0 < NROWS) atomicAdd(sumsim, ssim);
}

__global__ __launch_bounds__(1024) void finalize(const float* __restrict__ denom,
                                                 const float* __restrict__ sumsim,
                                                 float* __restrict__ out) {
  const int t = threadIdx.x;
  double s = 0.0;
#pragma unroll
  for (int i = t; i < NROWS; i += 1024) {
    s += (double)(NROWS - 1 - i) * log((double)denom[i]);
  }
#pragma unroll
  for (int m = 1; m < 64; m <<= 1) s += __shfl_xor(s, m);
  __shared__ double ws_[16];
  if ((t & 63) == 0) ws_[t >> 6] = s;
  __syncthreads();
  if (t == 0) {
    double tot = 0.0;
#pragma unroll
    for (int i = 0; i < 16; i++) tot += ws_[i];
    const double loss = tot - (double)sumsim[0];
    out[0] = (float)(-2.0 / (double)NROWS * (double)(NROWS - 1) * loss);
  }
}

extern "C" void kernel_launch(void* const* d_in, const int* in_sizes, int n_in,
                              void* d_out, int out_size, void* d_ws, size_t ws_size,
                              hipStream_t stream) {
  const float* emb = (const float*)d_in[0];
  unsigned char* zb = (unsigned char*)d_ws;
  float* denom = (float*)((char*)d_ws + (size_t)BROWS * BDIM);  // 8 MB fp8
  float* sumsim = denom + NROWS;
  float* out = (float*)d_out;

  normalize_kernel<<<BROWS / 4, 256, 0, stream>>>(emb, zb, denom, sumsim);
  gemm_fused<<<(NROWS / BM) * (BROWS / BN), 256, 0, stream>>>(zb, denom, sumsim);
  finalize<<<1, 1024, 0, stream>>>(denom, sumsim, out);
}

// Round 12
// 55.085 us; speedup vs baseline: 1.3061x; 1.1698x over previous
//
#include <hip/hip_runtime.h>
#include <stdint.h>

// ContrastiveLoss: B=8192, D=1024, n=2048, T=0.5
// K1: row-normalize f32 -> fp8 e4m3, PRE-SWIZZLED row-major layout
//     (16B chunk c of row r stored at position c^(r&7) within its 128B window)
// K2: 256x256-tile MX-fp8 GEMM, 1024 threads (16 waves, 4x4), acc 64/thread,
//     double-buffered LDS (128KB), linear gload_lds staging, 1 sync per K-tile,
//     XCD-chunked mapping; epilogue: exp-row-sum + triu sum
// K3: scalar finalize

#define BDIM 1024
#define BROWS 8192
#define NROWS 2048

#define BM 256
#define BN 256
#define BKB 128            // fp8 K-bytes per tile
#define NKT (BDIM / BKB)   // 8

typedef __attribute__((ext_vector_type(4))) int i32x4;
typedef __attribute__((ext_vector_type(8))) int i32x8;
typedef __attribute__((ext_vector_type(4))) float f32x4;

// float -> OCP e4m3fn, RNE, handles subnormals (|x| <= 1 for our data)
static __device__ __forceinline__ unsigned char f2e4m3(float x) {
  uint32_t u = __float_as_uint(x);
  uint32_t s = (u >> 24) & 0x80u;
  uint32_t a = u & 0x7fffffffu;
  if (a == 0) return (unsigned char)s;
  int e = (int)(a >> 23) - 127;
  uint32_t m = a & 0x7fffffu;
  if (e >= -6) {
    uint32_t keep = m >> 20;
    uint32_t rest = m & 0xfffffu;
    keep += (rest > 0x80000u) || (rest == 0x80000u && (keep & 1u));
    uint32_t v = ((uint32_t)(e + 7) << 3) + keep;
    return (unsigned char)(s | v);
  }
  if (e < -10) return (unsigned char)s;
  uint32_t full = 0x800000u | m;
  int sh = 14 - e;
  uint32_t keep = full >> sh;
  uint32_t rest = full & ((1u << sh) - 1u);
  uint32_t half = 1u << (sh - 1);
  keep += (rest > half) || (rest == half && (keep & 1u));
  return (unsigned char)(s | keep);
}

static __device__ __forceinline__ void gload_lds16(const unsigned char* g, unsigned char* l) {
  __builtin_amdgcn_global_load_lds(
      (const __attribute__((address_space(1))) uint32_t*)(const void*)g,
      (__attribute__((address_space(3))) uint32_t*)(void*)l,
      16, 0, 0);
}

static __device__ __forceinline__ uint32_t pk4(float4 v, float inv) {
  return (uint32_t)f2e4m3(v.x * inv) | ((uint32_t)f2e4m3(v.y * inv) << 8) |
         ((uint32_t)f2e4m3(v.z * inv) << 16) | ((uint32_t)f2e4m3(v.w * inv) << 24);
}

__global__ __launch_bounds__(256) void normalize_kernel(const float* __restrict__ emb,
                                                        unsigned char* __restrict__ zb,
                                                        float* __restrict__ denom,
                                                        float* __restrict__ sumsim) {
  const int w = threadIdx.x >> 6;
  const int lane = threadIdx.x & 63;
  const int row = blockIdx.x * 4 + w;
  const float4* src = reinterpret_cast<const float4*>(emb + (size_t)row * BDIM);
  float4 v[4];
  float ss = 0.f;
#pragma unroll
  for (int i = 0; i < 4; i++) {
    v[i] = src[lane * 4 + i];
    ss += v[i].x * v[i].x + v[i].y * v[i].y + v[i].z * v[i].z + v[i].w * v[i].w;
  }
#pragma unroll
  for (int m = 1; m < 64; m <<= 1) ss += __shfl_xor(ss, m);
  const float inv = rsqrtf(ss);
  uint4 o;
  o.x = pk4(v[0], inv);
  o.y = pk4(v[1], inv);
  o.z = pk4(v[2], inv);
  o.w = pk4(v[3], inv);
  // pre-swizzle: logical chunk (lane) stored at position (lane&56)|((lane&7)^(row&7))
  const int cp = (lane & 56) | ((lane & 7) ^ (row & 7));
  *reinterpret_cast<uint4*>(zb + (size_t)row * BDIM + cp * 16) = o;
  if (blockIdx.x < NROWS / 4 && lane == 0) denom[row] = 0.f;
  if (blockIdx.x == 0 && threadIdx.x == 0) sumsim[0] = 0.f;
}

// ---------------- GEMM ----------------
// zb PRE-SWIZZLED: position p of row r holds logical chunk p^(r&7).
// Staging linear -> LDS inherits swizzle -> frag reads apply chunk^(row&7).
// 16 waves: wave w = (WR,WC) in 4x4, owns 64x64 output. Per K-tile per wave:
// 4 gload_lds (2 A-rows-groups + 2 B), 8 frag-read pairs, 16 MFMA.

__global__ __launch_bounds__(1024) void gemm_fused(const unsigned char* __restrict__ zb,
                                                   float* __restrict__ denom,
                                                   float* __restrict__ sumsim) {
  __shared__ unsigned char As[2][BM * BKB];   // 2 x 32 KB
  __shared__ unsigned char Bs[2][BN * BKB];   // 2 x 32 KB

  // XCD-chunked: xcd owns 4 j-blocks x all 8 i-blocks (A 2MB + B 1MB < 4MB L2)
  const int bx = blockIdx.x;            // 0..255
  const int xcd = bx & 7;
  const int idx = bx >> 3;              // 0..31
  const int jb = xcd * 4 + (idx & 3);   // 0..31
  const int ib = idx >> 2;              // 0..7
  const int i0 = ib * BM;               // [0,2048)
  const int j0 = jb * BN;               // [0,8192)

  const int t = threadIdx.x;
  const int lane = t & 63;
  const int w = t >> 6;                 // 0..15
  const int WR = w >> 2;                // 0..3
  const int WC = w & 3;                 // 0..3

  // staging: each gload = 8 rows x 128B, linear ascending source
  const int rsh = lane >> 3;
  const int lin = (lane & 7) * 16;
  const int aw = w * 16;                // wave stages rows [w*16, +16) of A and B

  // fragment reads
  const int q2 = lane >> 4;             // 0..3 -> k-chunks {2q2, 2q2+1}
  const int rsub = lane & 15;
  const int rk = rsub & 7;

  f32x4 acc[4][4] = {};

#define STG_A(buf, r0, kk) \
  gload_lds16(zb + (size_t)(i0 + (r0) + aw + rsh) * BDIM + (kk) + lin, &As[buf][((r0) + aw) * BKB])
#define STG_B(buf, r0, kk) \
  gload_lds16(zb + (size_t)(j0 + (r0) + aw + rsh) * BDIM + (kk) + lin, &Bs[buf][((r0) + aw) * BKB])

#define RD_FRAG(dst, base, row)                                                                                  \
  {                                                                                                              \
    const i32x4 lo = *reinterpret_cast<const i32x4*>(&base[(size_t)(row) * BKB + (((2 * q2) ^ rk) * 16)]);       \
    const i32x4 hi = *reinterpret_cast<const i32x4*>(&base[(size_t)(row) * BKB + (((2 * q2 + 1) ^ rk) * 16)]);   \
    dst[0] = lo[0]; dst[1] = lo[1]; dst[2] = lo[2]; dst[3] = lo[3];                                              \
    dst[4] = hi[0]; dst[5] = hi[1]; dst[6] = hi[2]; dst[7] = hi[3];                                              \
  }

#define STAGE_TILE(buf, kk)                        \
  {                                                \
    STG_A(buf, 0, kk); STG_A(buf, 8, kk);          \
    STG_B(buf, 0, kk); STG_B(buf, 8, kk);          \
  }

  // ---- prologue ----
  STAGE_TILE(0, 0);
  __syncthreads();

  int cur = 0;
#pragma unroll 1
  for (int kt = 0; kt < NKT; ++kt) {
    const int nb = cur ^ 1;
    if (kt + 1 < NKT) STAGE_TILE(nb, (kt + 1) * BKB);

    i32x8 bb[4];
#pragma unroll
    for (int nn = 0; nn < 4; nn++) {
      RD_FRAG(bb[nn], (&Bs[cur][0]), WC * 64 + nn * 16 + rsub);
    }
    __builtin_amdgcn_s_setprio(1);
#pragma unroll
    for (int mm = 0; mm < 4; mm++) {
      i32x8 aa;
      RD_FRAG(aa, (&As[cur][0]), WR * 64 + mm * 16 + rsub);
#pragma unroll
      for (int nn = 0; nn < 4; nn++) {
        acc[mm][nn] = __builtin_amdgcn_mfma_scale_f32_16x16x128_f8f6f4(
            aa, bb[nn], acc[mm][nn], 0, 0, 0, 0x7f7f7f7f, 0, 0x7f7f7f7f);
      }
    }
    __builtin_amdgcn_s_setprio(0);

    __syncthreads();  // tile boundary: staged nb landed, cur reads done
    cur = nb;
  }

  // ---- epilogue: C/D layout col=lane&15, row=(lane>>4)*4+reg ----
  const int hi4 = lane >> 4;
  const int col_l = lane & 15;
  float ssim = 0.f;
#pragma unroll
  for (int m = 0; m < 4; m++) {
    const int gibase = i0 + WR * 64 + m * 16 + hi4 * 4;
#pragma unroll
    for (int r = 0; r < 4; r++) {
      const int gi = gibase + r;
      float dsum = 0.f;
#pragma unroll
      for (int n = 0; n < 4; n++) {
        const int gj = j0 + WC * 64 + n * 16 + col_l;
        const float s = acc[m][n][r] * 2.0f;
        const float e = __expf(s);
        if (gj != gi) dsum += e;               // denom excludes diagonal
        if (gj < NROWS && gi < gj) ssim += s;  // triu(rows[:, :n], k=1)
      }
      dsum += __shfl_xor(dsum, 1);
      dsum += __shfl_xor(dsum, 2);
      dsum += __shfl_xor(dsum, 4);
      dsum += __shfl_xor(dsum, 8);
      if (col_l == 0) atomicAdd(&denom[gi], dsum);
    }
  }
#pragma unroll
  for (int msk = 1; msk < 64; msk <<= 1) ssim += __shfl_xor(ssim, msk);
  if (lane == 0 && j0 < NROWS) atomicAdd(sumsim, ssim);
}

__global__ __launch_bounds__(1024) void finalize(const float* __restrict__ denom,
                                                 const float* __restrict__ sumsim,
                                                 float* __restrict__ out) {
  const int t = threadIdx.x;
  double s = 0.0;
#pragma unroll
  for (int i = t; i < NROWS; i += 1024) {
    s += (double)(NROWS - 1 - i) * log((double)denom[i]);
  }
#pragma unroll
  for (int m = 1; m < 64; m <<= 1) s += __shfl_xor(s, m);
  __shared__ double ws_[16];
  if ((t & 63) == 0) ws_[t >> 6] = s;
  __syncthreads();
  if (t == 0) {
    double tot = 0.0;
#pragma unroll
    for (int i = 0; i < 16; i++) tot += ws_[i];
    const double loss = tot - (double)sumsim[0];
    out[0] = (float)(-2.0 / (double)NROWS * (double)(NROWS - 1) * loss);
  }
}

extern "C" void kernel_launch(void* const* d_in, const int* in_sizes, int n_in,
                              void* d_out, int out_size, void* d_ws, size_t ws_size,
                              hipStream_t stream) {
  const float* emb = (const float*)d_in[0];
  unsigned char* zb = (unsigned char*)d_ws;
  float* denom = (float*)((char*)d_ws + (size_t)BROWS * BDIM);  // 8 MB fp8
  float* sumsim = denom + NROWS;
  float* out = (float*)d_out;

  normalize_kernel<<<BROWS / 4, 256, 0, stream>>>(emb, zb, denom, sumsim);
  gemm_fused<<<(NROWS / BM) * (BROWS / BN), 1024, 0, stream>>>(zb, denom, sumsim);
  finalize<<<1, 1024, 0, stream>>>(denom, sumsim, out);
}